// Round 4
// baseline (343.918 us; speedup 1.0000x reference)
//
#include <hip/hip_runtime.h>
#include <math.h>

// Problem constants (SpiralDeblock)
#define B      16
#define N_IN   7000
#define N_OUT  28000
#define C      64          // C_IN == C_OUT == 64
#define S      9
#define NNZ    (3 * N_OUT) // 84000
#define F      (S * C)     // 576
#define KB     (F / 32)    // 18 k-blocks of 32 for mfma 16x16x32

#define MT     110         // m-tiles in spiral_mfma: ceil(28000/256), 256 rows/block

typedef short bf16x8 __attribute__((ext_vector_type(8)));  // 8 bf16 = 4 VGPRs
typedef float f32x4  __attribute__((ext_vector_type(4)));

// fp32 -> bf16 round-to-nearest-even (bit pattern as ushort)
static __device__ __forceinline__ unsigned short f2bf(float f) {
    unsigned u = __float_as_uint(f);
    u += 0x7fffu + ((u >> 16) & 1u);
    return (unsigned short)(u >> 16);
}

// ---------------------------------------------------------------------------
// CSR build: histogram -> exclusive scan -> placement.
// ---------------------------------------------------------------------------
__global__ void hist_kernel(const int* __restrict__ row, int* __restrict__ cnt) {
    int i = blockIdx.x * 256 + threadIdx.x;
    if (i < NNZ) atomicAdd(&cnt[row[i]], 1);
}

// 1024 threads; thread t owns rows [t*28, t*28+28) (t<1000; 1000*28==28000).
__global__ void scan_kernel(const int* __restrict__ cnt,
                            int* __restrict__ offs, int* __restrict__ cursor) {
    __shared__ int tmp[1024];
    const int t = threadIdx.x;
    const int base = t * 28;
    const bool live = (t < 1000);

    int c[28];
    int partial = 0;
    if (live) {
        #pragma unroll
        for (int j = 0; j < 28; ++j) { c[j] = cnt[base + j]; partial += c[j]; }
    }
    tmp[t] = partial;
    __syncthreads();
    #pragma unroll
    for (int off = 1; off < 1024; off <<= 1) {
        int v = (t >= off) ? tmp[t - off] : 0;
        __syncthreads();
        tmp[t] += v;
        __syncthreads();
    }
    if (live) {
        int run = tmp[t] - partial;   // exclusive prefix
        #pragma unroll
        for (int j = 0; j < 28; ++j) {
            offs[base + j]   = run;
            cursor[base + j] = run;
            run += c[j];
        }
        if (t == 999) offs[N_OUT] = run;
    }
}

__global__ void place_kernel(const int* __restrict__ row, const int* __restrict__ col,
                             const float* __restrict__ values,
                             int* __restrict__ cursor,
                             int* __restrict__ ecol, float* __restrict__ eval) {
    int i = blockIdx.x * 256 + threadIdx.x;
    if (i < NNZ) {
        int pos = atomicAdd(&cursor[row[i]], 1);
        ecol[pos] = col[i];
        eval[pos] = values[i];
    }
}

// ---------------------------------------------------------------------------
// Batch-interleave transpose: xT[n][b][c] = x[b][n][c], fp32.
// Block = one n: thread t -> (b = t>>4, ch = (t&15)*4). Reads are 16
// coalesced 256 B streams; write is one contiguous 4 KB chunk.
// Makes every pool-kernel edge gather a CONTIGUOUS 4 KB read (R4 theory:
// pool was in the same scattered-line miss-parallelism regime as spiral).
// ---------------------------------------------------------------------------
__global__ void xt_kernel(const float* __restrict__ x, float* __restrict__ xT) {
    const int n  = blockIdx.x;            // 0..6999
    const int t  = threadIdx.x;           // 0..255
    const int b  = t >> 4;
    const int ch = (t & 15) * 4;
    const float4 v = *(const float4*)(x + ((size_t)b * N_IN + n) * C + ch);
    *(float4*)(xT + ((size_t)n * B + b) * C + ch) = v;
}

// ---------------------------------------------------------------------------
// Pooling, fully streaming. One wave per output row r, ALL 16 batches.
// Per edge: one contiguous 4 KB read of xT[cl][*][*] via 4 coalesced
// dwordx4 loads (lane i, instr j -> float4 at j*1024B + lane*16B; covers
// b = j*4 + (lane>>4), c = (lane&15)*4). Accumulate 4 float4/lane.
// Write: one contiguous 2 KB bf16 row pooled[r][b][c] (nontemporal; the
// pooled stream is consumed later by spiral from L2/L3).
// No scattered lines anywhere -> not bound by per-CU miss parallelism.
// ---------------------------------------------------------------------------
__global__ void pool_kernel(const float* __restrict__ xT,
                            const int*   __restrict__ ecol,
                            const float* __restrict__ eval,
                            const int*   __restrict__ offs,
                            unsigned short* __restrict__ pooled) {
    const int wave = threadIdx.x >> 6;
    const int lane = threadIdx.x & 63;
    const int r    = blockIdx.x * 4 + wave;   // 7000 blocks * 4 == 28000

    const int start = offs[r], end = offs[r + 1];

    float4 acc[4];
    #pragma unroll
    for (int j = 0; j < 4; ++j) acc[j] = make_float4(0.f, 0.f, 0.f, 0.f);

    for (int e = start; e < end; ++e) {
        const int   cl = ecol[e];
        const float v  = eval[e];
        const float* base = xT + (size_t)cl * (B * C) + lane * 4;
        float4 xv[4];
        #pragma unroll
        for (int j = 0; j < 4; ++j)
            xv[j] = *(const float4*)(base + j * 256);
        #pragma unroll
        for (int j = 0; j < 4; ++j) {
            acc[j].x = fmaf(xv[j].x, v, acc[j].x);
            acc[j].y = fmaf(xv[j].y, v, acc[j].y);
            acc[j].z = fmaf(xv[j].z, v, acc[j].z);
            acc[j].w = fmaf(xv[j].w, v, acc[j].w);
        }
    }

    unsigned short* dst = pooled + (size_t)r * (B * C) + lane * 4;
    #pragma unroll
    for (int j = 0; j < 4; ++j) {
        unsigned long long ov =
            (unsigned long long)f2bf(acc[j].x)
            | ((unsigned long long)f2bf(acc[j].y) << 16)
            | ((unsigned long long)f2bf(acc[j].z) << 32)
            | ((unsigned long long)f2bf(acc[j].w) << 48);
        __builtin_nontemporal_store(ov, (unsigned long long*)(dst + j * 256));
    }
}

// ---------------------------------------------------------------------------
// Pack weight (576x64 fp32, row-major [f][o]) into MFMA B-fragment lane order:
// packedW[((kb*4 + nt)*64 + lane)*8 + j] = bf16( W[(kb*32 + quad*8 + j)*64 + nt*16 + lm] )
// ---------------------------------------------------------------------------
__global__ void packw_kernel(const float* __restrict__ w, unsigned short* __restrict__ pw) {
    const int kb   = blockIdx.x;        // 0..17
    const int nt   = threadIdx.x >> 6;  // 0..3
    const int lane = threadIdx.x & 63;
    const int lm   = lane & 15;
    const int quad = lane >> 4;

    unsigned short v[8];
    #pragma unroll
    for (int j = 0; j < 8; ++j) {
        const int k = kb * 32 + quad * 8 + j;
        const int n = nt * 16 + lm;
        v[j] = f2bf(w[(size_t)k * C + n]);
    }
    unsigned short* dst = pw + ((size_t)(kb * 4 + nt) * 64 + lane) * 8;
    #pragma unroll
    for (int j = 0; j < 8; ++j) dst[j] = v[j];
}

// ---------------------------------------------------------------------------
// Gathered GEMM via MFMA 16x16x32 bf16, XCD-pinned by batch (b%8 == L%8).
// pooled layout is now [r][b][c]: each (r,b) is one aligned 128 B line, so
// the per-XCD working set is still 3.58 MB (only b==xcd lines touched) and
// the A-gather line count is identical to R3. B staged in LDS (R3).
// Known wall (R3 post-mortem): scattered A-lines at ~0.06 lines/cyc/CU =
// per-CU miss-parallelism cap; left unchanged this round.
// A-frag: lane holds A[m=lane&15][k=quad*8+j] -> one 16 B load from the
//         gathered pooled row, double-buffered across s.
// C/D:    col = lane&15, row = quad*4 + reg. Nontemporal out stores.
// ---------------------------------------------------------------------------
__global__ __launch_bounds__(512, 4)
void spiral_mfma(const unsigned short* __restrict__ pooled,
                 const bf16x8*         __restrict__ packedW,
                 const int*            __restrict__ sp,
                 const float*          __restrict__ bias,
                 float*                __restrict__ out) {
    const int L = blockIdx.x;               // 0 .. 16*MT-1
    int b, mtile;
    if (L < 8 * MT) { b = L & 7;                  mtile = L >> 3; }
    else            { b = 8 + ((L - 8 * MT) & 7); mtile = (L - 8 * MT) >> 3; }

    const int wave = threadIdx.x >> 6;      // 0..7
    const int lane = threadIdx.x & 63;
    const int lm   = lane & 15;
    const int quad = lane >> 4;
    const int m_base = mtile * 256 + wave * 32;

    // Stage full packed B (72 KB) into LDS: 512 thr x 16 B x 9 iters.
    __shared__ bf16x8 bw[KB * 4 * 64];      // 4608 frags = 73728 B
    {
        const int t = threadIdx.x;
        #pragma unroll
        for (int i = 0; i < 9; ++i)
            bw[i * 512 + t] = packedW[i * 512 + t];
    }

    // Lane i (mod 32) pre-loads sp[m_base+i, 0..8]; distributed via shfl.
    int spv[S];
    {
        int r = m_base + (lane & 31);
        if (r >= N_OUT) r = N_OUT - 1;
        #pragma unroll
        for (int s = 0; s < S; ++s) spv[s] = sp[r * S + s];
    }

    // pooled[r][b][c]: batch-b base offset in shorts.
    const unsigned short* poolb = pooled + (size_t)b * C;

    f32x4 acc[2][4];
    #pragma unroll
    for (int t = 0; t < 2; ++t)
        #pragma unroll
        for (int nt = 0; nt < 4; ++nt)
            acc[t][nt] = (f32x4){0.f, 0.f, 0.f, 0.f};

    int    rowi[2][2];
    bf16x8 abuf[2][2][2];   // [buf][half][t]

    // Prologue: A-frags for s = 0.
    #pragma unroll
    for (int t = 0; t < 2; ++t)
        rowi[0][t] = __shfl(spv[0], t * 16 + lm, 64);
    #pragma unroll
    for (int half = 0; half < 2; ++half) {
        const int c0 = half * 32 + quad * 8;
        #pragma unroll
        for (int t = 0; t < 2; ++t)
            abuf[0][half][t] =
                *(const bf16x8*)(poolb + (size_t)rowi[0][t] * (B * C) + c0);
    }

    __syncthreads();   // B staged (writes above, reads below)

    #pragma unroll
    for (int s = 0; s < S; ++s) {
        const int cur = s & 1, nxt = cur ^ 1;

        // Prefetch s+1's A-frags before consuming s (only VMEM in the loop).
        if (s + 1 < S) {
            #pragma unroll
            for (int t = 0; t < 2; ++t)
                rowi[nxt][t] = __shfl(spv[s + 1], t * 16 + lm, 64);
            #pragma unroll
            for (int half = 0; half < 2; ++half) {
                const int c0 = half * 32 + quad * 8;
                #pragma unroll
                for (int t = 0; t < 2; ++t)
                    abuf[nxt][half][t] =
                        *(const bf16x8*)(poolb + (size_t)rowi[nxt][t] * (B * C) + c0);
            }
        }

        // B-frags from LDS per half (keeps live regs ~16 for B).
        #pragma unroll
        for (int half = 0; half < 2; ++half) {
            bf16x8 bb[4];
            #pragma unroll
            for (int nt = 0; nt < 4; ++nt)
                bb[nt] = bw[((s * 2 + half) * 4 + nt) * 64 + lane];
            #pragma unroll
            for (int nt = 0; nt < 4; ++nt)
                #pragma unroll
                for (int t = 0; t < 2; ++t)
                    acc[t][nt] = __builtin_amdgcn_mfma_f32_16x16x32_bf16(
                        abuf[cur][half][t], bb[nt], acc[t][nt], 0, 0, 0);
        }
    }

    // Epilogue: bias + ELU + nontemporal store (out is a pure 114 MB stream).
    #pragma unroll
    for (int nt = 0; nt < 4; ++nt) {
        const int n = nt * 16 + lm;
        const float bs = bias[n];
        #pragma unroll
        for (int t = 0; t < 2; ++t) {
            #pragma unroll
            for (int reg = 0; reg < 4; ++reg) {
                const int r = m_base + t * 16 + quad * 4 + reg;
                if (r < N_OUT) {
                    float v = acc[t][nt][reg] + bs;
                    v = v > 0.f ? v : (__expf(v) - 1.0f);
                    __builtin_nontemporal_store(v,
                        out + ((size_t)b * N_OUT + r) * C + n);
                }
            }
        }
    }
}

// ---------------------------------------------------------------------------
// Launch.
// Inputs: 0:x 1:values 2:weight 3:bias 4:row 5:col 6:spiral_indices
// Workspace ~87 MB (<= 114.7 MB proven available).
// ---------------------------------------------------------------------------
extern "C" void kernel_launch(void* const* d_in, const int* in_sizes, int n_in,
                              void* d_out, int out_size, void* d_ws, size_t ws_size,
                              hipStream_t stream) {
    const float* x      = (const float*)d_in[0];
    const float* values = (const float*)d_in[1];
    const float* weight = (const float*)d_in[2];
    const float* bias   = (const float*)d_in[3];
    const int*   row    = (const int*)d_in[4];
    const int*   col    = (const int*)d_in[5];
    const int*   sp     = (const int*)d_in[6];
    float*       out    = (float*)d_out;

    char* ws = (char*)d_ws;
    size_t off = 0;
    unsigned short* pooled  = (unsigned short*)(ws + off); off += (size_t)N_OUT * B * C * 2;      // 57,344,000
    unsigned short* packedW = (unsigned short*)(ws + off); off += (size_t)KB * 4 * 64 * 8 * 2;    // 73,728
    float* xT     = (float*)(ws + off); off += (size_t)N_IN * B * C * 4;                          // 28,672,000
    int*   offs   = (int*)(ws + off); off += ((size_t)(N_OUT + 1) * 4 + 124) / 128 * 128;
    int*   cursor = (int*)(ws + off); off += (size_t)N_OUT * 4 + 128;
    int*   cnt    = (int*)(ws + off); off += (size_t)N_OUT * 4 + 128;
    int*   ecol   = (int*)(ws + off); off += (size_t)NNZ * 4;
    float* eval   = (float*)(ws + off); off += (size_t)NNZ * 4;

    // CSR build (cnt must start at zero; ws is poisoned each call).
    (void)hipMemsetAsync(cnt, 0, (size_t)N_OUT * 4, stream);
    hist_kernel <<<(NNZ + 255) / 256, 256, 0, stream>>>(row, cnt);
    scan_kernel <<<1, 1024, 0, stream>>>(cnt, offs, cursor);
    place_kernel<<<(NNZ + 255) / 256, 256, 0, stream>>>(row, col, values, cursor, ecol, eval);

    // Pack weight into MFMA B-fragment order (independent of CSR chain).
    packw_kernel<<<KB, 256, 0, stream>>>(weight, packedW);

    // Batch-interleave x (independent of CSR chain).
    xt_kernel<<<N_IN, 256, 0, stream>>>(x, xT);

    // Pool into bf16 [r][b][c]: fully streaming (4 KB/edge contiguous).
    pool_kernel<<<N_OUT / 4, 256, 0, stream>>>(xT, ecol, eval, offs, pooled);

    // Gathered GEMM + bias + ELU (B in LDS, XCD-pinned by batch).
    spiral_mfma<<<B * MT, 512, 0, stream>>>(pooled,
        reinterpret_cast<const bf16x8*>(packedW), sp, bias, out);
}

// Round 5
// 321.006 us; speedup vs baseline: 1.0714x; 1.0714x over previous
//
#include <hip/hip_runtime.h>
#include <math.h>

// Problem constants (SpiralDeblock)
#define B      16
#define N_IN   7000
#define N_OUT  28000
#define C      64          // C_IN == C_OUT == 64
#define S      9
#define NNZ    (3 * N_OUT) // 84000
#define F      (S * C)     // 576
#define KB     (F / 32)    // 18 k-blocks of 32 for mfma 16x16x32

typedef short bf16x8 __attribute__((ext_vector_type(8)));  // 8 bf16 = 4 VGPRs
typedef float f32x4  __attribute__((ext_vector_type(4)));

// fp32 -> bf16 round-to-nearest-even (bit pattern as ushort)
static __device__ __forceinline__ unsigned short f2bf(float f) {
    unsigned u = __float_as_uint(f);
    u += 0x7fffu + ((u >> 16) & 1u);
    return (unsigned short)(u >> 16);
}

// ---------------------------------------------------------------------------
// CSR build: histogram -> exclusive scan -> placement.
// ---------------------------------------------------------------------------
__global__ void hist_kernel(const int* __restrict__ row, int* __restrict__ cnt) {
    int i = blockIdx.x * 256 + threadIdx.x;
    if (i < NNZ) atomicAdd(&cnt[row[i]], 1);
}

// 1024 threads; thread t owns rows [t*28, t*28+28) (t<1000; 1000*28==28000).
__global__ void scan_kernel(const int* __restrict__ cnt,
                            int* __restrict__ offs, int* __restrict__ cursor) {
    __shared__ int tmp[1024];
    const int t = threadIdx.x;
    const int base = t * 28;
    const bool live = (t < 1000);

    int c[28];
    int partial = 0;
    if (live) {
        #pragma unroll
        for (int j = 0; j < 28; ++j) { c[j] = cnt[base + j]; partial += c[j]; }
    }
    tmp[t] = partial;
    __syncthreads();
    #pragma unroll
    for (int off = 1; off < 1024; off <<= 1) {
        int v = (t >= off) ? tmp[t - off] : 0;
        __syncthreads();
        tmp[t] += v;
        __syncthreads();
    }
    if (live) {
        int run = tmp[t] - partial;   // exclusive prefix
        #pragma unroll
        for (int j = 0; j < 28; ++j) {
            offs[base + j]   = run;
            cursor[base + j] = run;
            run += c[j];
        }
        if (t == 999) offs[N_OUT] = run;
    }
}

__global__ void place_kernel(const int* __restrict__ row, const int* __restrict__ col,
                             const float* __restrict__ values,
                             int* __restrict__ cursor,
                             int* __restrict__ ecol, float* __restrict__ eval) {
    int i = blockIdx.x * 256 + threadIdx.x;
    if (i < NNZ) {
        int pos = atomicAdd(&cursor[row[i]], 1);
        ecol[pos] = col[i];
        eval[pos] = values[i];
    }
}

// ---------------------------------------------------------------------------
// Batch-interleave transpose: xT[n][b][c] = x[b][n][c], fp32.
// Block = one n: thread t -> (b = t>>4, ch = (t&15)*4). Reads are 16
// coalesced 256 B streams; write is one contiguous 4 KB chunk.
// ---------------------------------------------------------------------------
__global__ void xt_kernel(const float* __restrict__ x, float* __restrict__ xT) {
    const int n  = blockIdx.x;            // 0..6999
    const int t  = threadIdx.x;           // 0..255
    const int b  = t >> 4;
    const int ch = (t & 15) * 4;
    const float4 v = *(const float4*)(x + ((size_t)b * N_IN + n) * C + ch);
    *(float4*)(xT + ((size_t)n * B + b) * C + ch) = v;
}

// ---------------------------------------------------------------------------
// Pooling, fully streaming. One wave per output row r, ALL 16 batches.
// Per edge: one contiguous 4 KB read of xT[cl][*][*] (4 coalesced dwordx4
// loads). Write: pooled in [g][r][b'][c] bf16 layout (g = b>>3 outer so
// that a (g,r) chunk is 1 KB contiguous with full set-index coverage --
// R4's [r][b][c] froze addr bits [10:7] per batch = 16x set aliasing).
// ---------------------------------------------------------------------------
__global__ void pool_kernel(const float* __restrict__ xT,
                            const int*   __restrict__ ecol,
                            const float* __restrict__ eval,
                            const int*   __restrict__ offs,
                            unsigned short* __restrict__ pooled) {
    const int wave = threadIdx.x >> 6;
    const int lane = threadIdx.x & 63;
    const int r    = blockIdx.x * 4 + wave;   // 7000 blocks * 4 == 28000

    const int start = offs[r], end = offs[r + 1];

    float4 acc[4];
    #pragma unroll
    for (int j = 0; j < 4; ++j) acc[j] = make_float4(0.f, 0.f, 0.f, 0.f);

    for (int e = start; e < end; ++e) {
        const int   cl = ecol[e];
        const float v  = eval[e];
        const float* base = xT + (size_t)cl * (B * C) + lane * 4;
        float4 xv[4];
        #pragma unroll
        for (int j = 0; j < 4; ++j)
            xv[j] = *(const float4*)(base + j * 256);
        #pragma unroll
        for (int j = 0; j < 4; ++j) {
            acc[j].x = fmaf(xv[j].x, v, acc[j].x);
            acc[j].y = fmaf(xv[j].y, v, acc[j].y);
            acc[j].z = fmaf(xv[j].z, v, acc[j].z);
            acc[j].w = fmaf(xv[j].w, v, acc[j].w);
        }
    }

    // acc[j] covers batch b = j*4 + (lane>>4), channels (lane&15)*4 .. +3.
    // pooled short-offset = g*N_OUT*512 + r*512 + b'*64 + c.
    #pragma unroll
    for (int j = 0; j < 4; ++j) {
        const int g  = j >> 1;
        const int bp = (j & 1) * 4 + (lane >> 4);
        unsigned long long ov =
            (unsigned long long)f2bf(acc[j].x)
            | ((unsigned long long)f2bf(acc[j].y) << 16)
            | ((unsigned long long)f2bf(acc[j].z) << 32)
            | ((unsigned long long)f2bf(acc[j].w) << 48);
        unsigned short* dst = pooled + (size_t)g * (N_OUT * 512)
                            + (size_t)r * 512 + bp * 64 + (lane & 15) * 4;
        __builtin_nontemporal_store(ov, (unsigned long long*)dst);
    }
}

// ---------------------------------------------------------------------------
// Pack weight (576x64 fp32, row-major [f][o]) into MFMA B-fragment lane order:
// packedW[((kb*4 + nt)*64 + lane)*8 + j] = bf16( W[(kb*32 + quad*8 + j)*64 + nt*16 + lm] )
// ---------------------------------------------------------------------------
__global__ void packw_kernel(const float* __restrict__ w, unsigned short* __restrict__ pw) {
    const int kb   = blockIdx.x;        // 0..17
    const int nt   = threadIdx.x >> 6;  // 0..3
    const int lane = threadIdx.x & 63;
    const int lm   = lane & 15;
    const int quad = lane >> 4;

    unsigned short v[8];
    #pragma unroll
    for (int j = 0; j < 8; ++j) {
        const int k = kb * 32 + quad * 8 + j;
        const int n = nt * 16 + lm;
        v[j] = f2bf(w[(size_t)k * C + n]);
    }
    unsigned short* dst = pw + ((size_t)(kb * 4 + nt) * 64 + lane) * 8;
    #pragma unroll
    for (int j = 0; j < 8; ++j) dst[j] = v[j];
}

// ---------------------------------------------------------------------------
// Gathered GEMM, cross-batch-shared gathers (R5 redesign).
// R4 post-mortem: spiral is latency x concurrency bound on scattered
// 64-128 B gathers; per-CU outstanding-request cap is shared (R1: 2x waves
// gave no gain). Fix: sp indices are batch-independent, so a block now
// processes ONE 32-row m-tile x 8 batches (wave w = batch g*8+w). Each
// gathered row is a CONTIGUOUS 1 KB chunk pooled[g][r][*][*], loaded by a
// single fully-coalesced 64-lane x 16 B instruction and staged to LDS
// (double-buffered, XOR-swizzled chunks: stored_chunk = chunk ^ (rowslot&7)
// to break the stride-1024 bank pattern on frag reads). 16x more bytes per
// outstanding request; ~256 lines in flight per block.
// Pipeline per stage (T14): issue s+1 chunk loads -> ds_read A/B frags +
// 16 MFMAs for s -> (vmcnt drain) ds_write s+1 -> barrier.
// B (72 KB) staged in LDS once. LDS total 136 KB -> 1 block/CU.
// A-frag: lane (lm,quad) reads chunk w*8 + ((half*4+quad)^(rowslot&7)).
// C/D:    col = lane&15, row = quad*4 + reg. Nontemporal out stores.
// ---------------------------------------------------------------------------
__global__ __launch_bounds__(512, 2)
void spiral_mfma(const unsigned short* __restrict__ pooled,
                 const bf16x8*         __restrict__ packedW,
                 const int*            __restrict__ sp,
                 const float*          __restrict__ bias,
                 float*                __restrict__ out) {
    const int Lb    = blockIdx.x;           // 0..1749
    const int g     = Lb & 1;               // batch group (8 batches)
    const int mtile = Lb >> 1;              // 0..874 (875*32 == 28000)
    const int wave  = threadIdx.x >> 6;     // 0..7 == batch within group
    const int lane  = threadIdx.x & 63;
    const int lm    = lane & 15;
    const int quad  = lane >> 4;
    const int m_base = mtile * 32;
    const int b      = g * 8 + wave;

    __shared__ bf16x8         bw[KB * 4 * 64];      // 73728 B
    __shared__ unsigned short apool[2][32][512];    // 65536 B (2 x 32 x 1KB)

    // Stage packed B (72 KB): 512 thr x 16 B x 9 iters.
    {
        const int t = threadIdx.x;
        #pragma unroll
        for (int i = 0; i < 9; ++i)
            bw[i * 512 + t] = packedW[i * 512 + t];
    }

    // Lane i (i<32) holds sp[m_base+i][s]; same content in every wave.
    int spv[S];
    {
        const int r = m_base + (lane & 31);
        #pragma unroll
        for (int s = 0; s < S; ++s) spv[s] = sp[r * S + s];
    }

    const unsigned short* pgbase = pooled + (size_t)g * (N_OUT * 512);

    f32x4 acc[2][4];
    #pragma unroll
    for (int t = 0; t < 2; ++t)
        #pragma unroll
        for (int nt = 0; nt < 4; ++nt)
            acc[t][nt] = (f32x4){0.f, 0.f, 0.f, 0.f};

    bf16x8 ld[4];   // staging regs: wave loads rows wave*4 .. wave*4+3

    // Prologue: stage s=0 chunks into buf 0.
    #pragma unroll
    for (int q = 0; q < 4; ++q) {
        const int r = __shfl(spv[0], wave * 4 + q, 64);
        ld[q] = *(const bf16x8*)(pgbase + (size_t)r * 512 + lane * 8);
    }
    #pragma unroll
    for (int q = 0; q < 4; ++q) {
        const int j = wave * 4 + q;
        *(bf16x8*)(&apool[0][j][(lane ^ (j & 7)) * 8]) = ld[q];
    }
    __syncthreads();   // B + A(s=0) staged

    #pragma unroll
    for (int s = 0; s < S; ++s) {
        const int cur = s & 1, nxt = cur ^ 1;

        // Issue s+1 chunk loads early (fully coalesced 1 KB per instr).
        if (s + 1 < S) {
            #pragma unroll
            for (int q = 0; q < 4; ++q) {
                const int r = __shfl(spv[s + 1], wave * 4 + q, 64);
                ld[q] = *(const bf16x8*)(pgbase + (size_t)r * 512 + lane * 8);
            }
        }

        // Compute stage s: A-frags + B-frags from LDS, 16 MFMAs.
        #pragma unroll
        for (int half = 0; half < 2; ++half) {
            bf16x8 bb[4];
            #pragma unroll
            for (int nt = 0; nt < 4; ++nt)
                bb[nt] = bw[((s * 2 + half) * 4 + nt) * 64 + lane];
            bf16x8 aa[2];
            #pragma unroll
            for (int t = 0; t < 2; ++t) {
                const int j = t * 16 + lm;
                const int chunk = wave * 8 + (((half * 4 + quad) ^ (j & 7)));
                aa[t] = *(const bf16x8*)(&apool[cur][j][chunk * 8]);
            }
            #pragma unroll
            for (int nt = 0; nt < 4; ++nt)
                #pragma unroll
                for (int t = 0; t < 2; ++t)
                    acc[t][nt] = __builtin_amdgcn_mfma_f32_16x16x32_bf16(
                        aa[t], bb[nt], acc[t][nt], 0, 0, 0);
        }

        // Write-late: drain loads, stage s+1 into buf nxt.
        if (s + 1 < S) {
            #pragma unroll
            for (int q = 0; q < 4; ++q) {
                const int j = wave * 4 + q;
                *(bf16x8*)(&apool[nxt][j][(lane ^ (j & 7)) * 8]) = ld[q];
            }
        }
        __syncthreads();
    }

    // Epilogue: bias + ELU + nontemporal store (out is a pure stream).
    #pragma unroll
    for (int nt = 0; nt < 4; ++nt) {
        const int n = nt * 16 + lm;
        const float bs = bias[n];
        #pragma unroll
        for (int t = 0; t < 2; ++t) {
            #pragma unroll
            for (int reg = 0; reg < 4; ++reg) {
                const int r = m_base + t * 16 + quad * 4 + reg;
                float v = acc[t][nt][reg] + bs;
                v = v > 0.f ? v : (__expf(v) - 1.0f);
                __builtin_nontemporal_store(v,
                    out + ((size_t)b * N_OUT + r) * C + n);
            }
        }
    }
}

// ---------------------------------------------------------------------------
// Launch.
// Inputs: 0:x 1:values 2:weight 3:bias 4:row 5:col 6:spiral_indices
// Workspace ~87 MB.
// ---------------------------------------------------------------------------
extern "C" void kernel_launch(void* const* d_in, const int* in_sizes, int n_in,
                              void* d_out, int out_size, void* d_ws, size_t ws_size,
                              hipStream_t stream) {
    const float* x      = (const float*)d_in[0];
    const float* values = (const float*)d_in[1];
    const float* weight = (const float*)d_in[2];
    const float* bias   = (const float*)d_in[3];
    const int*   row    = (const int*)d_in[4];
    const int*   col    = (const int*)d_in[5];
    const int*   sp     = (const int*)d_in[6];
    float*       out    = (float*)d_out;

    char* ws = (char*)d_ws;
    size_t off = 0;
    unsigned short* pooled  = (unsigned short*)(ws + off); off += (size_t)B * N_OUT * C * 2;      // 57,344,000
    unsigned short* packedW = (unsigned short*)(ws + off); off += (size_t)KB * 4 * 64 * 8 * 2;    // 73,728
    float* xT     = (float*)(ws + off); off += (size_t)N_IN * B * C * 4;                          // 28,672,000
    int*   offs   = (int*)(ws + off); off += ((size_t)(N_OUT + 1) * 4 + 124) / 128 * 128;
    int*   cursor = (int*)(ws + off); off += (size_t)N_OUT * 4 + 128;
    int*   cnt    = (int*)(ws + off); off += (size_t)N_OUT * 4 + 128;
    int*   ecol   = (int*)(ws + off); off += (size_t)NNZ * 4;
    float* eval   = (float*)(ws + off); off += (size_t)NNZ * 4;

    // CSR build (cnt must start at zero; ws is poisoned each call).
    (void)hipMemsetAsync(cnt, 0, (size_t)N_OUT * 4, stream);
    hist_kernel <<<(NNZ + 255) / 256, 256, 0, stream>>>(row, cnt);
    scan_kernel <<<1, 1024, 0, stream>>>(cnt, offs, cursor);
    place_kernel<<<(NNZ + 255) / 256, 256, 0, stream>>>(row, col, values, cursor, ecol, eval);

    // Pack weight into MFMA B-fragment order (independent of CSR chain).
    packw_kernel<<<KB, 256, 0, stream>>>(weight, packedW);

    // Batch-interleave x (independent of CSR chain).
    xt_kernel<<<N_IN, 256, 0, stream>>>(x, xT);

    // Pool into bf16 [g][r][b'][c]: streaming reads, 1 KB group-chunks.
    pool_kernel<<<N_OUT / 4, 256, 0, stream>>>(xT, ecol, eval, offs, pooled);

    // Gathered GEMM + bias + ELU: 875 m-tiles x 2 batch groups; block =
    // 32 rows x 8 batches; gathers shared across batches via LDS.
    spiral_mfma<<<875 * 2, 512, 0, stream>>>(pooled,
        reinterpret_cast<const bf16x8*>(packedW), sp, bias, out);
}

// Round 6
// 300.322 us; speedup vs baseline: 1.1452x; 1.0689x over previous
//
#include <hip/hip_runtime.h>
#include <math.h>

// Problem constants (SpiralDeblock)
#define B      16
#define N_IN   7000
#define N_OUT  28000
#define C      64          // C_IN == C_OUT == 64
#define S      9
#define NNZ    (3 * N_OUT) // 84000
#define F      (S * C)     // 576
#define KB     (F / 32)    // 18 k-blocks of 32 for mfma 16x16x32

typedef short bf16x8 __attribute__((ext_vector_type(8)));  // 8 bf16 = 4 VGPRs
typedef float f32x4  __attribute__((ext_vector_type(4)));

// fp32 -> bf16 round-to-nearest-even (bit pattern as ushort)
static __device__ __forceinline__ unsigned short f2bf(float f) {
    unsigned u = __float_as_uint(f);
    u += 0x7fffu + ((u >> 16) & 1u);
    return (unsigned short)(u >> 16);
}

// ---------------------------------------------------------------------------
// CSR build: histogram -> exclusive scan -> placement.
// ---------------------------------------------------------------------------
__global__ void hist_kernel(const int* __restrict__ row, int* __restrict__ cnt) {
    int i = blockIdx.x * 256 + threadIdx.x;
    if (i < NNZ) atomicAdd(&cnt[row[i]], 1);
}

// 1024 threads; thread t owns rows [t*28, t*28+28) (t<1000; 1000*28==28000).
__global__ void scan_kernel(const int* __restrict__ cnt,
                            int* __restrict__ offs, int* __restrict__ cursor) {
    __shared__ int tmp[1024];
    const int t = threadIdx.x;
    const int base = t * 28;
    const bool live = (t < 1000);

    int c[28];
    int partial = 0;
    if (live) {
        #pragma unroll
        for (int j = 0; j < 28; ++j) { c[j] = cnt[base + j]; partial += c[j]; }
    }
    tmp[t] = partial;
    __syncthreads();
    #pragma unroll
    for (int off = 1; off < 1024; off <<= 1) {
        int v = (t >= off) ? tmp[t - off] : 0;
        __syncthreads();
        tmp[t] += v;
        __syncthreads();
    }
    if (live) {
        int run = tmp[t] - partial;   // exclusive prefix
        #pragma unroll
        for (int j = 0; j < 28; ++j) {
            offs[base + j]   = run;
            cursor[base + j] = run;
            run += c[j];
        }
        if (t == 999) offs[N_OUT] = run;
    }
}

__global__ void place_kernel(const int* __restrict__ row, const int* __restrict__ col,
                             const float* __restrict__ values,
                             int* __restrict__ cursor,
                             int* __restrict__ ecol, float* __restrict__ eval) {
    int i = blockIdx.x * 256 + threadIdx.x;
    if (i < NNZ) {
        int pos = atomicAdd(&cursor[row[i]], 1);
        ecol[pos] = col[i];
        eval[pos] = values[i];
    }
}

// ---------------------------------------------------------------------------
// Pooling, XCD-pinned by batch-pair (R6: back to L2-resident gathers).
// R5 post-mortem: pool-from-xT gathered a 28.7 MB slab randomly -> same
// per-CU L2-miss-fill wall as spiral (~3.2 TB/s on 344 MB ~= 100 us).
// Fix: XCD k (= blockIdx&7) owns batches {k, k+8}: x working set
// 2 x 1.79 MB = 3.58 MB < 4 MB L2 -> gathers are L2 HITS (34.5 TB/s
// regime, no MSHR pressure). x is read DIRECTLY (xt_kernel deleted).
// Wave: 2 rows (lane>>5) x 2 batches ((lane>>4)&1) x 16 sl; per edge one
// float4/lane = 4 chunks of 256 B. 4-edge batching breaks the dependent
// ecol->x chain. Writes: [g][r][bp][c] layout spiral expects; per
// (g,r,bp) a FULL 128 B line; nontemporal so the 57 MB write stream
// doesn't evict the pinned x slab.
// ---------------------------------------------------------------------------
__global__ void pool_kernel(const float* __restrict__ x,
                            const int*   __restrict__ ecol,
                            const float* __restrict__ eval,
                            const int*   __restrict__ offs,
                            unsigned short* __restrict__ pooled) {
    const int bg     = blockIdx.x & 7;    // batch group == XCD
    const int rowblk = blockIdx.x >> 3;   // 0..3499
    const int wave = threadIdx.x >> 6;
    const int lane = threadIdx.x & 63;
    const int rsub = lane >> 5;
    const int bsub = (lane >> 4) & 1;     // g (group) of batch bg + 8*bsub
    const int sl   = lane & 15;

    const int r = rowblk * 8 + wave * 2 + rsub;
    const int b = bg + 8 * bsub;

    const int start = offs[r], end = offs[r + 1];

    float4 acc = make_float4(0.f, 0.f, 0.f, 0.f);
    const float* xb = x + (size_t)b * N_IN * C + sl * 4;

    for (int e = start; e < end; e += 4) {
        const int nn = end - e;           // >= 1
        int   cl[4]; float vv[4];
        #pragma unroll
        for (int j = 0; j < 4; ++j) {
            const int ee = (j < nn) ? e + j : e;   // clamp: valid addr, weight 0
            cl[j] = ecol[ee];
            vv[j] = (j < nn) ? eval[ee] : 0.f;
        }
        float4 xv[4];
        #pragma unroll
        for (int j = 0; j < 4; ++j)
            xv[j] = *(const float4*)(xb + (size_t)cl[j] * C);
        #pragma unroll
        for (int j = 0; j < 4; ++j) {
            acc.x = fmaf(xv[j].x, vv[j], acc.x);
            acc.y = fmaf(xv[j].y, vv[j], acc.y);
            acc.z = fmaf(xv[j].z, vv[j], acc.z);
            acc.w = fmaf(xv[j].w, vv[j], acc.w);
        }
    }

    // pooled short-offset = g*N_OUT*512 + r*512 + bp*64 + c  (g=bsub, bp=bg).
    unsigned long long ov =
        (unsigned long long)f2bf(acc.x)
        | ((unsigned long long)f2bf(acc.y) << 16)
        | ((unsigned long long)f2bf(acc.z) << 32)
        | ((unsigned long long)f2bf(acc.w) << 48);
    unsigned short* dst = pooled + (size_t)bsub * (N_OUT * 512)
                        + (size_t)r * 512 + bg * 64 + sl * 4;
    __builtin_nontemporal_store(ov, (unsigned long long*)dst);
}

// ---------------------------------------------------------------------------
// Pack weight (576x64 fp32, row-major [f][o]) into MFMA B-fragment lane order:
// packedW[((kb*4 + nt)*64 + lane)*8 + j] = bf16( W[(kb*32 + quad*8 + j)*64 + nt*16 + lm] )
// ---------------------------------------------------------------------------
__global__ void packw_kernel(const float* __restrict__ w, unsigned short* __restrict__ pw) {
    const int kb   = blockIdx.x;        // 0..17
    const int nt   = threadIdx.x >> 6;  // 0..3
    const int lane = threadIdx.x & 63;
    const int lm   = lane & 15;
    const int quad = lane >> 4;

    unsigned short v[8];
    #pragma unroll
    for (int j = 0; j < 8; ++j) {
        const int k = kb * 32 + quad * 8 + j;
        const int n = nt * 16 + lm;
        v[j] = f2bf(w[(size_t)k * C + n]);
    }
    unsigned short* dst = pw + ((size_t)(kb * 4 + nt) * 64 + lane) * 8;
    #pragma unroll
    for (int j = 0; j < 8; ++j) dst[j] = v[j];
}

// ---------------------------------------------------------------------------
// Gathered GEMM, cross-batch-shared gathers (R5 structure, FROZEN in R6).
// R5 post-mortem: gather runs at the per-CU L2-miss fill wall (~4.5 TB/s
// effective, invariant across R3's L2-hit-scattered and R5's L3-coalesced
// configs); no L2-residency scheme exists for the 57 MB randomly-gathered
// pooled (4 MB L2/XCD). ~114 us is treated as spiral's structural floor
// at bf16.
// Block = 32 rows x 8 batches (wave = batch). Gathered row = contiguous
// 1 KB chunk pooled[g][r][*][*], one coalesced 64-lane x 16 B load, staged
// to LDS (double-buffered, chunk XOR-swizzle). B (72 KB) in LDS once.
// ---------------------------------------------------------------------------
__global__ __launch_bounds__(512, 2)
void spiral_mfma(const unsigned short* __restrict__ pooled,
                 const bf16x8*         __restrict__ packedW,
                 const int*            __restrict__ sp,
                 const float*          __restrict__ bias,
                 float*                __restrict__ out) {
    const int Lb    = blockIdx.x;           // 0..1749
    const int g     = Lb & 1;               // batch group (8 batches)
    const int mtile = Lb >> 1;              // 0..874 (875*32 == 28000)
    const int wave  = threadIdx.x >> 6;     // 0..7 == batch within group
    const int lane  = threadIdx.x & 63;
    const int lm    = lane & 15;
    const int quad  = lane >> 4;
    const int m_base = mtile * 32;
    const int b      = g * 8 + wave;

    __shared__ bf16x8         bw[KB * 4 * 64];      // 73728 B
    __shared__ unsigned short apool[2][32][512];    // 65536 B (2 x 32 x 1KB)

    // Stage packed B (72 KB): 512 thr x 16 B x 9 iters.
    {
        const int t = threadIdx.x;
        #pragma unroll
        for (int i = 0; i < 9; ++i)
            bw[i * 512 + t] = packedW[i * 512 + t];
    }

    // Lane i (i<32) holds sp[m_base+i][s]; same content in every wave.
    int spv[S];
    {
        const int r = m_base + (lane & 31);
        #pragma unroll
        for (int s = 0; s < S; ++s) spv[s] = sp[r * S + s];
    }

    const unsigned short* pgbase = pooled + (size_t)g * (N_OUT * 512);

    f32x4 acc[2][4];
    #pragma unroll
    for (int t = 0; t < 2; ++t)
        #pragma unroll
        for (int nt = 0; nt < 4; ++nt)
            acc[t][nt] = (f32x4){0.f, 0.f, 0.f, 0.f};

    bf16x8 ld[4];   // staging regs: wave loads rows wave*4 .. wave*4+3

    // Prologue: stage s=0 chunks into buf 0.
    #pragma unroll
    for (int q = 0; q < 4; ++q) {
        const int r = __shfl(spv[0], wave * 4 + q, 64);
        ld[q] = *(const bf16x8*)(pgbase + (size_t)r * 512 + lane * 8);
    }
    #pragma unroll
    for (int q = 0; q < 4; ++q) {
        const int j = wave * 4 + q;
        *(bf16x8*)(&apool[0][j][(lane ^ (j & 7)) * 8]) = ld[q];
    }
    __syncthreads();   // B + A(s=0) staged

    #pragma unroll
    for (int s = 0; s < S; ++s) {
        const int cur = s & 1, nxt = cur ^ 1;

        // Issue s+1 chunk loads early (fully coalesced 1 KB per instr).
        if (s + 1 < S) {
            #pragma unroll
            for (int q = 0; q < 4; ++q) {
                const int r = __shfl(spv[s + 1], wave * 4 + q, 64);
                ld[q] = *(const bf16x8*)(pgbase + (size_t)r * 512 + lane * 8);
            }
        }

        // Compute stage s: A-frags + B-frags from LDS, 16 MFMAs.
        #pragma unroll
        for (int half = 0; half < 2; ++half) {
            bf16x8 bb[4];
            #pragma unroll
            for (int nt = 0; nt < 4; ++nt)
                bb[nt] = bw[((s * 2 + half) * 4 + nt) * 64 + lane];
            bf16x8 aa[2];
            #pragma unroll
            for (int t = 0; t < 2; ++t) {
                const int j = t * 16 + lm;
                const int chunk = wave * 8 + (((half * 4 + quad) ^ (j & 7)));
                aa[t] = *(const bf16x8*)(&apool[cur][j][chunk * 8]);
            }
            #pragma unroll
            for (int nt = 0; nt < 4; ++nt)
                #pragma unroll
                for (int t = 0; t < 2; ++t)
                    acc[t][nt] = __builtin_amdgcn_mfma_f32_16x16x32_bf16(
                        aa[t], bb[nt], acc[t][nt], 0, 0, 0);
        }

        // Write-late: drain loads, stage s+1 into buf nxt.
        if (s + 1 < S) {
            #pragma unroll
            for (int q = 0; q < 4; ++q) {
                const int j = wave * 4 + q;
                *(bf16x8*)(&apool[nxt][j][(lane ^ (j & 7)) * 8]) = ld[q];
            }
        }
        __syncthreads();
    }

    // Epilogue: bias + ELU + nontemporal store (out is a pure stream).
    #pragma unroll
    for (int nt = 0; nt < 4; ++nt) {
        const int n = nt * 16 + lm;
        const float bs = bias[n];
        #pragma unroll
        for (int t = 0; t < 2; ++t) {
            #pragma unroll
            for (int reg = 0; reg < 4; ++reg) {
                const int r = m_base + t * 16 + quad * 4 + reg;
                float v = acc[t][nt][reg] + bs;
                v = v > 0.f ? v : (__expf(v) - 1.0f);
                __builtin_nontemporal_store(v,
                    out + ((size_t)b * N_OUT + r) * C + n);
            }
        }
    }
}

// ---------------------------------------------------------------------------
// Launch.
// Inputs: 0:x 1:values 2:weight 3:bias 4:row 5:col 6:spiral_indices
// Workspace ~58.4 MB (xT dropped).
// ---------------------------------------------------------------------------
extern "C" void kernel_launch(void* const* d_in, const int* in_sizes, int n_in,
                              void* d_out, int out_size, void* d_ws, size_t ws_size,
                              hipStream_t stream) {
    const float* x      = (const float*)d_in[0];
    const float* values = (const float*)d_in[1];
    const float* weight = (const float*)d_in[2];
    const float* bias   = (const float*)d_in[3];
    const int*   row    = (const int*)d_in[4];
    const int*   col    = (const int*)d_in[5];
    const int*   sp     = (const int*)d_in[6];
    float*       out    = (float*)d_out;

    char* ws = (char*)d_ws;
    size_t off = 0;
    unsigned short* pooled  = (unsigned short*)(ws + off); off += (size_t)B * N_OUT * C * 2;      // 57,344,000
    unsigned short* packedW = (unsigned short*)(ws + off); off += (size_t)KB * 4 * 64 * 8 * 2;    // 73,728
    int*   offs   = (int*)(ws + off); off += ((size_t)(N_OUT + 1) * 4 + 124) / 128 * 128;
    int*   cursor = (int*)(ws + off); off += (size_t)N_OUT * 4 + 128;
    int*   cnt    = (int*)(ws + off); off += (size_t)N_OUT * 4 + 128;
    int*   ecol   = (int*)(ws + off); off += (size_t)NNZ * 4;
    float* eval   = (float*)(ws + off); off += (size_t)NNZ * 4;

    // CSR build (cnt must start at zero; ws is poisoned each call).
    (void)hipMemsetAsync(cnt, 0, (size_t)N_OUT * 4, stream);
    hist_kernel <<<(NNZ + 255) / 256, 256, 0, stream>>>(row, cnt);
    scan_kernel <<<1, 1024, 0, stream>>>(cnt, offs, cursor);
    place_kernel<<<(NNZ + 255) / 256, 256, 0, stream>>>(row, col, values, cursor, ecol, eval);

    // Pack weight into MFMA B-fragment order (independent of CSR chain).
    packw_kernel<<<KB, 256, 0, stream>>>(weight, packedW);

    // Pool into bf16 [g][r][bp][c]: XCD-pinned batch pairs, x read direct
    // (L2-resident 3.58 MB/XCD), full-line NT writes.
    pool_kernel<<<3500 * 8, 256, 0, stream>>>(x, ecol, eval, offs, pooled);

    // Gathered GEMM + bias + ELU: 875 m-tiles x 2 batch groups; block =
    // 32 rows x 8 batches; gathers shared across batches via LDS.
    spiral_mfma<<<875 * 2, 512, 0, stream>>>(pooled,
        reinterpret_cast<const bf16x8*>(packedW), sp, bias, out);
}

// Round 7
// 296.260 us; speedup vs baseline: 1.1609x; 1.0137x over previous
//
#include <hip/hip_runtime.h>
#include <math.h>

// Problem constants (SpiralDeblock)
#define B      16
#define N_IN   7000
#define N_OUT  28000
#define C      64          // C_IN == C_OUT == 64
#define S      9
#define NNZ    (3 * N_OUT) // 84000
#define F      (S * C)     // 576
#define KB     (F / 32)    // 18 k-blocks of 32 for mfma 16x16x32

typedef short bf16x8 __attribute__((ext_vector_type(8)));  // 8 bf16 = 4 VGPRs
typedef float f32x4  __attribute__((ext_vector_type(4)));

// fp32 -> bf16 round-to-nearest-even (bit pattern as ushort)
static __device__ __forceinline__ unsigned short f2bf(float f) {
    unsigned u = __float_as_uint(f);
    u += 0x7fffu + ((u >> 16) & 1u);
    return (unsigned short)(u >> 16);
}
static __device__ __forceinline__ float bf2f(unsigned short s) {
    return __uint_as_float((unsigned)s << 16);
}

// ---------------------------------------------------------------------------
// CSR build: histogram -> exclusive scan -> placement.
// ---------------------------------------------------------------------------
__global__ void hist_kernel(const int* __restrict__ row, int* __restrict__ cnt) {
    int i = blockIdx.x * 256 + threadIdx.x;
    if (i < NNZ) atomicAdd(&cnt[row[i]], 1);
}

// 1024 threads; thread t owns rows [t*28, t*28+28) (t<1000; 1000*28==28000).
__global__ void scan_kernel(const int* __restrict__ cnt,
                            int* __restrict__ offs, int* __restrict__ cursor) {
    __shared__ int tmp[1024];
    const int t = threadIdx.x;
    const int base = t * 28;
    const bool live = (t < 1000);

    int c[28];
    int partial = 0;
    if (live) {
        #pragma unroll
        for (int j = 0; j < 28; ++j) { c[j] = cnt[base + j]; partial += c[j]; }
    }
    tmp[t] = partial;
    __syncthreads();
    #pragma unroll
    for (int off = 1; off < 1024; off <<= 1) {
        int v = (t >= off) ? tmp[t - off] : 0;
        __syncthreads();
        tmp[t] += v;
        __syncthreads();
    }
    if (live) {
        int run = tmp[t] - partial;   // exclusive prefix
        #pragma unroll
        for (int j = 0; j < 28; ++j) {
            offs[base + j]   = run;
            cursor[base + j] = run;
            run += c[j];
        }
        if (t == 999) offs[N_OUT] = run;
    }
}

__global__ void place_kernel(const int* __restrict__ row, const int* __restrict__ col,
                             const float* __restrict__ values,
                             int* __restrict__ cursor,
                             int* __restrict__ ecol, float* __restrict__ eval) {
    int i = blockIdx.x * 256 + threadIdx.x;
    if (i < NNZ) {
        int pos = atomicAdd(&cursor[row[i]], 1);
        ecol[pos] = col[i];
        eval[pos] = values[i];
    }
}

// ---------------------------------------------------------------------------
// x -> bf16 convert (R7): halves pool's gather bytes (the per-CU line-
// transaction wall is the cost currency: 5.4M -> 2.7M lines). Pure stream,
// 28.7 MB read / 14.3 MB write. 7,168,000 floats, 8 per thread.
// ---------------------------------------------------------------------------
__global__ void xbf_kernel(const float* __restrict__ x, unsigned short* __restrict__ xb) {
    const size_t i = ((size_t)blockIdx.x * 256 + threadIdx.x) * 8;
    const float4 a = *(const float4*)(x + i);
    const float4 c = *(const float4*)(x + i + 4);
    ushort4 o0, o1;
    o0.x = f2bf(a.x); o0.y = f2bf(a.y); o0.z = f2bf(a.z); o0.w = f2bf(a.w);
    o1.x = f2bf(c.x); o1.y = f2bf(c.y); o1.z = f2bf(c.z); o1.w = f2bf(c.w);
    *(ushort4*)(xb + i)     = o0;
    *(ushort4*)(xb + i + 4) = o1;
}

// ---------------------------------------------------------------------------
// Pooling from bf16 x, XCD-pinned by batch-pair (bg = blockIdx&7 owns
// batches {bg, bg+8}; xbf working set 1.79 MB/XCD, L2-resident).
// Wave: 2 rows (lane>>5) x 2 batches ((lane>>4)&1) x 16 sl; per edge one
// ushort4 (8 B) per lane = 128 B (2 lines) per (row,batch). 4-edge
// batching breaks the dependent ecol->x chain. Writes: [g][r][bp][c]
// layout spiral expects; full 128 B line per (g,r,bp); nontemporal.
// ---------------------------------------------------------------------------
__global__ void pool_kernel(const unsigned short* __restrict__ xb,
                            const int*   __restrict__ ecol,
                            const float* __restrict__ eval,
                            const int*   __restrict__ offs,
                            unsigned short* __restrict__ pooled) {
    const int bg     = blockIdx.x & 7;    // batch group == XCD
    const int rowblk = blockIdx.x >> 3;   // 0..3499
    const int wave = threadIdx.x >> 6;
    const int lane = threadIdx.x & 63;
    const int rsub = lane >> 5;
    const int bsub = (lane >> 4) & 1;     // g (group) of batch bg + 8*bsub
    const int sl   = lane & 15;

    const int r = rowblk * 8 + wave * 2 + rsub;
    const int b = bg + 8 * bsub;

    const int start = offs[r], end = offs[r + 1];

    float4 acc = make_float4(0.f, 0.f, 0.f, 0.f);
    const unsigned short* xbb = xb + (size_t)b * N_IN * C + sl * 4;

    for (int e = start; e < end; e += 4) {
        const int nn = end - e;           // >= 1
        int   cl[4]; float vv[4];
        #pragma unroll
        for (int j = 0; j < 4; ++j) {
            const int ee = (j < nn) ? e + j : e;   // clamp: valid addr, weight 0
            cl[j] = ecol[ee];
            vv[j] = (j < nn) ? eval[ee] : 0.f;
        }
        ushort4 xv[4];
        #pragma unroll
        for (int j = 0; j < 4; ++j)
            xv[j] = *(const ushort4*)(xbb + (size_t)cl[j] * C);
        #pragma unroll
        for (int j = 0; j < 4; ++j) {
            acc.x = fmaf(bf2f(xv[j].x), vv[j], acc.x);
            acc.y = fmaf(bf2f(xv[j].y), vv[j], acc.y);
            acc.z = fmaf(bf2f(xv[j].z), vv[j], acc.z);
            acc.w = fmaf(bf2f(xv[j].w), vv[j], acc.w);
        }
    }

    // pooled short-offset = g*N_OUT*512 + r*512 + bp*64 + c  (g=bsub, bp=bg).
    unsigned long long ov =
        (unsigned long long)f2bf(acc.x)
        | ((unsigned long long)f2bf(acc.y) << 16)
        | ((unsigned long long)f2bf(acc.z) << 32)
        | ((unsigned long long)f2bf(acc.w) << 48);
    unsigned short* dst = pooled + (size_t)bsub * (N_OUT * 512)
                        + (size_t)r * 512 + bg * 64 + sl * 4;
    __builtin_nontemporal_store(ov, (unsigned long long*)dst);
}

// ---------------------------------------------------------------------------
// Pack weight (576x64 fp32, row-major [f][o]) into MFMA B-fragment lane order:
// packedW[((kb*4 + nt)*64 + lane)*8 + j] = bf16( W[(kb*32 + quad*8 + j)*64 + nt*16 + lm] )
// ---------------------------------------------------------------------------
__global__ void packw_kernel(const float* __restrict__ w, unsigned short* __restrict__ pw) {
    const int kb   = blockIdx.x;        // 0..17
    const int nt   = threadIdx.x >> 6;  // 0..3
    const int lane = threadIdx.x & 63;
    const int lm   = lane & 15;
    const int quad = lane >> 4;

    unsigned short v[8];
    #pragma unroll
    for (int j = 0; j < 8; ++j) {
        const int k = kb * 32 + quad * 8 + j;
        const int n = nt * 16 + lm;
        v[j] = f2bf(w[(size_t)k * C + n]);
    }
    unsigned short* dst = pw + ((size_t)(kb * 4 + nt) * 64 + lane) * 8;
    #pragma unroll
    for (int j = 0; j < 8; ++j) dst[j] = v[j];
}

// ---------------------------------------------------------------------------
// Gathered GEMM, cross-batch-shared gathers. R7: the wall is per-CU
// in-flight line concurrency (R3 L2-hit scattered and R5 HBM coalesced
// both ran ~8M lines / ~117 us; hipcc's vmcnt(0) drain at __syncthreads
// empties the pipe each stage at 1 block/CU). Fix: per-stage B staging
// (8 KB double-buffered) instead of whole-B (72 KB) -> LDS 81,920 B ->
// 2 blocks/CU: while one block sits in its barrier drain, the other's 8
// waves issue gathers (cross-block overlap; no sync-structure change).
// Block = 32 rows x 8 batches (wave = batch). Gathered row = contiguous
// 1 KB chunk pooled[g][r][*][*], one coalesced 64-lane x 16 B load, staged
// to LDS (double-buffered, chunk XOR-swizzle).
// ---------------------------------------------------------------------------
__global__ __launch_bounds__(512, 4)
void spiral_mfma(const unsigned short* __restrict__ pooled,
                 const bf16x8*         __restrict__ packedW,
                 const int*            __restrict__ sp,
                 const float*          __restrict__ bias,
                 float*                __restrict__ out) {
    const int Lb    = blockIdx.x;           // 0..1749
    const int g     = Lb & 1;               // batch group (8 batches)
    const int mtile = Lb >> 1;              // 0..874 (875*32 == 28000)
    const int tid   = threadIdx.x;
    const int wave  = tid >> 6;             // 0..7 == batch within group
    const int lane  = tid & 63;
    const int lm    = lane & 15;
    const int quad  = lane >> 4;
    const int m_base = mtile * 32;
    const int b      = g * 8 + wave;

    __shared__ unsigned short apool[2][32][512];   // 65536 B (2 x 32 x 1KB)
    __shared__ bf16x8         bstage[2][512];      // 16384 B (2 x 8KB)
    // total 81920 B -> exactly 2 blocks/CU (160 KiB)

    // Lane i (i<32) holds sp[m_base+i][s]; same content in every wave.
    int spv[S];
    {
        const int r = m_base + (lane & 31);
        #pragma unroll
        for (int s = 0; s < S; ++s) spv[s] = sp[r * S + s];
    }

    const unsigned short* pgbase = pooled + (size_t)g * (N_OUT * 512);

    f32x4 acc[2][4];
    #pragma unroll
    for (int t = 0; t < 2; ++t)
        #pragma unroll
        for (int nt = 0; nt < 4; ++nt)
            acc[t][nt] = (f32x4){0.f, 0.f, 0.f, 0.f};

    bf16x8 ldA[4];   // A staging regs: wave loads rows wave*4 .. wave*4+3
    bf16x8 ldB;      // B staging reg: thread t covers 16 B of the 8 KB stage

    // Prologue: stage s=0 (A chunks + B stage) into buf 0.
    #pragma unroll
    for (int q = 0; q < 4; ++q) {
        const int r = __shfl(spv[0], wave * 4 + q, 64);
        ldA[q] = *(const bf16x8*)(pgbase + (size_t)r * 512 + lane * 8);
    }
    ldB = packedW[tid];
    #pragma unroll
    for (int q = 0; q < 4; ++q) {
        const int j = wave * 4 + q;
        *(bf16x8*)(&apool[0][j][(lane ^ (j & 7)) * 8]) = ldA[q];
    }
    bstage[0][tid] = ldB;
    __syncthreads();

    #pragma unroll
    for (int s = 0; s < S; ++s) {
        const int cur = s & 1, nxt = cur ^ 1;

        // Issue s+1 loads early (A: coalesced 1 KB chunks; B: 8 KB stream).
        if (s + 1 < S) {
            #pragma unroll
            for (int q = 0; q < 4; ++q) {
                const int r = __shfl(spv[s + 1], wave * 4 + q, 64);
                ldA[q] = *(const bf16x8*)(pgbase + (size_t)r * 512 + lane * 8);
            }
            ldB = packedW[(s + 1) * 512 + tid];
        }

        // Compute stage s: A-frags + B-frags from LDS, 16 MFMAs.
        #pragma unroll
        for (int half = 0; half < 2; ++half) {
            bf16x8 bb[4];
            #pragma unroll
            for (int nt = 0; nt < 4; ++nt)
                bb[nt] = bstage[cur][(half * 4 + nt) * 64 + lane];
            bf16x8 aa[2];
            #pragma unroll
            for (int t = 0; t < 2; ++t) {
                const int j = t * 16 + lm;
                const int chunk = wave * 8 + (((half * 4 + quad) ^ (j & 7)));
                aa[t] = *(const bf16x8*)(&apool[cur][j][chunk * 8]);
            }
            #pragma unroll
            for (int nt = 0; nt < 4; ++nt)
                #pragma unroll
                for (int t = 0; t < 2; ++t)
                    acc[t][nt] = __builtin_amdgcn_mfma_f32_16x16x32_bf16(
                        aa[t], bb[nt], acc[t][nt], 0, 0, 0);
        }

        // Write-late: drain loads, stage s+1 into buf nxt.
        if (s + 1 < S) {
            #pragma unroll
            for (int q = 0; q < 4; ++q) {
                const int j = wave * 4 + q;
                *(bf16x8*)(&apool[nxt][j][(lane ^ (j & 7)) * 8]) = ldA[q];
            }
            bstage[nxt][tid] = ldB;
        }
        __syncthreads();
    }

    // Epilogue: bias + ELU + nontemporal store (out is a pure stream).
    #pragma unroll
    for (int nt = 0; nt < 4; ++nt) {
        const int n = nt * 16 + lm;
        const float bs = bias[n];
        #pragma unroll
        for (int t = 0; t < 2; ++t) {
            #pragma unroll
            for (int reg = 0; reg < 4; ++reg) {
                const int r = m_base + t * 16 + quad * 4 + reg;
                float v = acc[t][nt][reg] + bs;
                v = v > 0.f ? v : (__expf(v) - 1.0f);
                __builtin_nontemporal_store(v,
                    out + ((size_t)b * N_OUT + r) * C + n);
            }
        }
    }
}

// ---------------------------------------------------------------------------
// Launch.
// Inputs: 0:x 1:values 2:weight 3:bias 4:row 5:col 6:spiral_indices
// Workspace ~73 MB (<= 114.7 MB proven available).
// ---------------------------------------------------------------------------
extern "C" void kernel_launch(void* const* d_in, const int* in_sizes, int n_in,
                              void* d_out, int out_size, void* d_ws, size_t ws_size,
                              hipStream_t stream) {
    const float* x      = (const float*)d_in[0];
    const float* values = (const float*)d_in[1];
    const float* weight = (const float*)d_in[2];
    const float* bias   = (const float*)d_in[3];
    const int*   row    = (const int*)d_in[4];
    const int*   col    = (const int*)d_in[5];
    const int*   sp     = (const int*)d_in[6];
    float*       out    = (float*)d_out;

    char* ws = (char*)d_ws;
    size_t off = 0;
    unsigned short* pooled  = (unsigned short*)(ws + off); off += (size_t)B * N_OUT * C * 2;      // 57,344,000
    unsigned short* packedW = (unsigned short*)(ws + off); off += (size_t)KB * 4 * 64 * 8 * 2;    // 73,728
    unsigned short* xbf     = (unsigned short*)(ws + off); off += (size_t)B * N_IN * C * 2;       // 14,336,000
    int*   offs   = (int*)(ws + off); off += ((size_t)(N_OUT + 1) * 4 + 124) / 128 * 128;
    int*   cursor = (int*)(ws + off); off += (size_t)N_OUT * 4 + 128;
    int*   cnt    = (int*)(ws + off); off += (size_t)N_OUT * 4 + 128;
    int*   ecol   = (int*)(ws + off); off += (size_t)NNZ * 4;
    float* eval   = (float*)(ws + off); off += (size_t)NNZ * 4;

    // CSR build (cnt must start at zero; ws is poisoned each call).
    (void)hipMemsetAsync(cnt, 0, (size_t)N_OUT * 4, stream);
    hist_kernel <<<(NNZ + 255) / 256, 256, 0, stream>>>(row, cnt);
    scan_kernel <<<1, 1024, 0, stream>>>(cnt, offs, cursor);
    place_kernel<<<(NNZ + 255) / 256, 256, 0, stream>>>(row, col, values, cursor, ecol, eval);

    // Pack weight into MFMA B-fragment order (independent of CSR chain).
    packw_kernel<<<KB, 256, 0, stream>>>(weight, packedW);

    // x -> bf16 (independent of CSR chain). 7,168,000 floats / 8 / 256.
    xbf_kernel<<<3500, 256, 0, stream>>>(x, xbf);

    // Pool into bf16 [g][r][bp][c]: XCD-pinned batch pairs, bf16 gathers
    // (half the line-transactions), full-line NT writes.
    pool_kernel<<<3500 * 8, 256, 0, stream>>>(xbf, ecol, eval, offs, pooled);

    // Gathered GEMM + bias + ELU: 875 m-tiles x 2 batch groups; block =
    // 32 rows x 8 batches; gathers shared across batches via LDS;
    // 81,920 B LDS -> 2 blocks/CU for cross-block gather overlap.
    spiral_mfma<<<875 * 2, 512, 0, stream>>>(pooled,
        reinterpret_cast<const bf16x8*>(packedW), sp, bias, out);
}